// Round 1
// baseline (69.392 us; speedup 1.0000x reference)
//
#include <hip/hip_runtime.h>

#define ODE_UNFOLDS 6
#define LTC_EPS 1e-8f

// One thread per (batch b, pair j<d). Units j and p=j+d form an independent
// 2-unit recurrence: mask couples only (j,j),(p,j),(p,p),(j,p); sensory row j
// feeds only columns j and p. All per-synapse constants are folded so each
// sigmoid is: fma -> v_exp_f32 -> add -> v_rcp_f32.
__global__ __launch_bounds__(64)
void ltc_pair_kernel(const float* __restrict__ inputs,
                     const float* __restrict__ input_w, const float* __restrict__ input_b,
                     const float* __restrict__ output_w, const float* __restrict__ output_b,
                     const float* __restrict__ gleak, const float* __restrict__ vleak,
                     const float* __restrict__ cm,
                     const float* __restrict__ w, const float* __restrict__ mu,
                     const float* __restrict__ sigma, const float* __restrict__ erev,
                     const float* __restrict__ sw, const float* __restrict__ smu,
                     const float* __restrict__ ssig, const float* __restrict__ serev,
                     float* __restrict__ out,
                     int B, int T, int d)
{
    const int tid = blockIdx.x * blockDim.x + threadIdx.x;
    const int total = B * d;
    if (tid >= total) return;
    const int b = tid / d;
    const int j = tid - b * d;
    const int units = 2 * d;
    const int p = j + d;

    const float LOG2E = 1.4426950408889634f;

    // --- fold recurrent synapse constants: z2 = v*A + C ; e = exp2(z2); s = 1/(1+e)
    // A = -sigma*LOG2E, C = mu*sigma*LOG2E ; WE = w*erev
    float A_jj, C_jj, W_jj, WE_jj;
    float A_pj, C_pj, W_pj, WE_pj;
    float A_pp, C_pp, W_pp, WE_pp;
    float A_jp, C_jp, W_jp, WE_jp;
    {
        int i;
        i = j * units + j;  { float sg = sigma[i], m = mu[i]; A_jj = -sg * LOG2E; C_jj = m * sg * LOG2E; W_jj = w[i]; WE_jj = W_jj * erev[i]; }
        i = p * units + j;  { float sg = sigma[i], m = mu[i]; A_pj = -sg * LOG2E; C_pj = m * sg * LOG2E; W_pj = w[i]; WE_pj = W_pj * erev[i]; }
        i = p * units + p;  { float sg = sigma[i], m = mu[i]; A_pp = -sg * LOG2E; C_pp = m * sg * LOG2E; W_pp = w[i]; WE_pp = W_pp * erev[i]; }
        i = j * units + p;  { float sg = sigma[i], m = mu[i]; A_jp = -sg * LOG2E; C_jp = m * sg * LOG2E; W_jp = w[i]; WE_jp = W_jp * erev[i]; }
    }

    const float cmj  = cm[j] * (float)ODE_UNFOLDS;
    const float cmp_ = cm[p] * (float)ODE_UNFOLDS;
    const float glj  = gleak[j], glp = gleak[p];
    const float gvj  = glj * vleak[j], gvp = glp * vleak[p];
    const float cglj = cmj + glj, cglp = cmp_ + glp;

    // --- sensory synapses: row j -> cols j and p
    float sA_j, sC_j, sW_j, sWE_j, sA_p, sC_p, sW_p, sWE_p;
    {
        int i;
        i = j * units + j; { float sg = ssig[i], m = smu[i]; sA_j = -sg * LOG2E; sC_j = m * sg * LOG2E; sW_j = sw[i]; sWE_j = sW_j * serev[i]; }
        i = j * units + p; { float sg = ssig[i], m = smu[i]; sA_p = -sg * LOG2E; sC_p = m * sg * LOG2E; sW_p = sw[i]; sWE_p = sW_p * serev[i]; }
    }

    const float iw = input_w[j], ib = input_b[j];

    const float* __restrict__ xin = inputs + (size_t)b * T * d + j;

    float vj = 0.f, vp = 0.f;

    const int TU = 4;                 // software-pipeline depth for x loads
    float xbuf[TU];
#pragma unroll
    for (int k = 0; k < TU; ++k) xbuf[k] = xin[(size_t)k * d];

    for (int g = 0; g < T; g += TU) {
        float xnext[TU];
        if (g + TU < T) {
#pragma unroll
            for (int k = 0; k < TU; ++k) xnext[k] = xin[(size_t)(g + TU + k) * d];
        } else {
#pragma unroll
            for (int k = 0; k < TU; ++k) xnext[k] = 0.f;
        }

#pragma unroll
        for (int k = 0; k < TU; ++k) {
            const float x = fmaf(xbuf[k], iw, ib);
            // sensory sigmoids (once per timestep)
            const float ssj = __builtin_amdgcn_rcpf(1.f + __builtin_amdgcn_exp2f(fmaf(x, sA_j, sC_j)));
            const float ssp = __builtin_amdgcn_rcpf(1.f + __builtin_amdgcn_exp2f(fmaf(x, sA_p, sC_p)));
            const float num_base_j = fmaf(sWE_j, ssj, gvj);
            const float den_base_j = fmaf(sW_j,  ssj, cglj);
            const float num_base_p = fmaf(sWE_p, ssp, gvp);
            const float den_base_p = fmaf(sW_p,  ssp, cglp);

#pragma unroll
            for (int u = 0; u < ODE_UNFOLDS; ++u) {
                const float s_jj = __builtin_amdgcn_rcpf(1.f + __builtin_amdgcn_exp2f(fmaf(vj, A_jj, C_jj)));
                const float s_pj = __builtin_amdgcn_rcpf(1.f + __builtin_amdgcn_exp2f(fmaf(vp, A_pj, C_pj)));
                const float s_pp = __builtin_amdgcn_rcpf(1.f + __builtin_amdgcn_exp2f(fmaf(vp, A_pp, C_pp)));
                const float s_jp = __builtin_amdgcn_rcpf(1.f + __builtin_amdgcn_exp2f(fmaf(vj, A_jp, C_jp)));

                float numj = fmaf(cmj, vj, num_base_j);
                numj = fmaf(WE_jj, s_jj, numj);
                numj = fmaf(WE_pj, s_pj, numj);
                float denj = fmaf(W_jj, s_jj, den_base_j);
                denj = fmaf(W_pj, s_pj, denj);

                float nump = fmaf(cmp_, vp, num_base_p);
                nump = fmaf(WE_pp, s_pp, nump);
                nump = fmaf(WE_jp, s_jp, nump);
                float denp = fmaf(W_pp, s_pp, den_base_p);
                denp = fmaf(W_jp, s_jp, denp);

                vj = numj * __builtin_amdgcn_rcpf(denj + LTC_EPS);
                vp = nump * __builtin_amdgcn_rcpf(denp + LTC_EPS);
            }
        }

#pragma unroll
        for (int k = 0; k < TU; ++k) xbuf[k] = xnext[k];
    }

    out[(size_t)b * d + j] = fmaf(vj, output_w[j], output_b[j]);
}

extern "C" void kernel_launch(void* const* d_in, const int* in_sizes, int n_in,
                              void* d_out, int out_size, void* d_ws, size_t ws_size,
                              hipStream_t stream) {
    const float* inputs   = (const float*)d_in[0];
    const float* input_w  = (const float*)d_in[1];
    const float* input_b  = (const float*)d_in[2];
    const float* output_w = (const float*)d_in[3];
    const float* output_b = (const float*)d_in[4];
    const float* gleak    = (const float*)d_in[5];
    const float* vleak    = (const float*)d_in[6];
    const float* cm       = (const float*)d_in[7];
    const float* w        = (const float*)d_in[8];
    const float* mu       = (const float*)d_in[9];
    const float* sigma    = (const float*)d_in[10];
    const float* erev     = (const float*)d_in[11];
    const float* sw       = (const float*)d_in[12];
    const float* smu      = (const float*)d_in[13];
    const float* ssig     = (const float*)d_in[14];
    const float* serev    = (const float*)d_in[15];
    float* out = (float*)d_out;

    const int d = in_sizes[1];            // input_w has shape (d,)
    const int B = out_size / d;           // out is (B, d)
    const int T = in_sizes[0] / (B * d);  // inputs is (B, T, d)

    const int total = B * d;              // one thread per (b, pair)
    const int block = 64;
    const int grid = (total + block - 1) / block;
    ltc_pair_kernel<<<grid, block, 0, stream>>>(
        inputs, input_w, input_b, output_w, output_b,
        gleak, vleak, cm, w, mu, sigma, erev,
        sw, smu, ssig, serev, out, B, T, d);
}

// Round 2
// 43.675 us; speedup vs baseline: 1.5888x; 1.5888x over previous
//
#include <hip/hip_runtime.h>

#define ODE_UNFOLDS 6
#define LTC_EPS 1e-8f

// Two lanes per (batch b, pair j<d): lane h=0 owns unit j, lane h=1 owns unit
// p=j+d (adjacent lanes -> partner exchange is a quad_perm DPP mov, no LDS).
// Each lane evaluates its unit's 2 incoming sigmoids (self + cross) with the
// paired-rcp trick: 1/(1+e1),1/(1+e2) from one rcp of the product.
// All per-synapse constants folded: sigmoid arg = fma(v, A, C) with
// A=-sigma*log2e, C=mu*sigma*log2e; input affine folded into sensory consts.

__device__ __forceinline__ float swap_pair(float x) {
    // quad_perm [1,0,3,2] : lane XOR 1, single full-rate v_mov_b32 dpp
    return __int_as_float(
        __builtin_amdgcn_mov_dpp(__float_as_int(x), 0xB1, 0xF, 0xF, true));
}

__global__ __launch_bounds__(64)
void ltc_lane_kernel(const float* __restrict__ inputs,
                     const float* __restrict__ input_w, const float* __restrict__ input_b,
                     const float* __restrict__ output_w, const float* __restrict__ output_b,
                     const float* __restrict__ gleak, const float* __restrict__ vleak,
                     const float* __restrict__ cm,
                     const float* __restrict__ w, const float* __restrict__ mu,
                     const float* __restrict__ sigma, const float* __restrict__ erev,
                     const float* __restrict__ sw, const float* __restrict__ smu,
                     const float* __restrict__ ssig, const float* __restrict__ serev,
                     float* __restrict__ out,
                     int B, int T, int d)
{
    const int tid = blockIdx.x * blockDim.x + threadIdx.x;
    const int units = 2 * d;
    if (tid >= B * units) return;

    const int pairIdx = tid >> 1;
    const int h = tid & 1;                 // 0 -> unit j, 1 -> unit j+d
    const int b = pairIdx / d;
    const int j = pairIdx - b * d;
    const int u  = j + h * d;              // my unit
    const int pu = j + (1 - h) * d;        // partner unit

    const float LOG2E = 1.4426950408889634f;

    // recurrent synapses into unit u: self (u->u) and cross (pu->u)
    float A_s, C_s, W_s, WE_s, A_c, C_c, W_c, WE_c;
    {
        int i = u * units + u;
        float sg = sigma[i], m = mu[i];
        A_s = -sg * LOG2E; C_s = m * sg * LOG2E; W_s = w[i]; WE_s = W_s * erev[i];
        i = pu * units + u;
        sg = sigma[i]; m = mu[i];
        A_c = -sg * LOG2E; C_c = m * sg * LOG2E; W_c = w[i]; WE_c = W_c * erev[i];
    }

    // sensory synapse j -> u, with input affine folded in:
    // arg = (x*iw+ib)*sA + sC = x*(iw*sA) + (ib*sA + sC)
    float siA, siC, sW, sWE;
    {
        int i = j * units + u;
        float sg = ssig[i], m = smu[i];
        float sA = -sg * LOG2E, sC = m * sg * LOG2E;
        const float iw = input_w[j], ib = input_b[j];
        siA = iw * sA; siC = ib * sA + sC;
        sW = sw[i]; sWE = sW * serev[i];
    }

    const float cmu = cm[u] * (float)ODE_UNFOLDS;
    const float gl  = gleak[u];
    const float gv  = gl * vleak[u];
    const float den0 = cmu + gl + LTC_EPS;   // EPS folded into den base

    const float* __restrict__ xin = inputs + (size_t)b * T * d + j;

    float v = 0.f;

    const int TU = 4;                      // software-pipeline depth for x loads
    float xbuf[TU];
#pragma unroll
    for (int k = 0; k < TU; ++k) xbuf[k] = xin[(size_t)k * d];

    for (int g = 0; g < T; g += TU) {
        float xnext[TU];
        if (g + TU < T) {
#pragma unroll
            for (int k = 0; k < TU; ++k) xnext[k] = xin[(size_t)(g + TU + k) * d];
        } else {
#pragma unroll
            for (int k = 0; k < TU; ++k) xnext[k] = 0.f;
        }

#pragma unroll
        for (int k = 0; k < TU; ++k) {
            // sensory sigmoid (independent of v: hoistable by scheduler)
            const float es = __builtin_amdgcn_exp2f(fmaf(xbuf[k], siA, siC));
            const float ss = __builtin_amdgcn_rcpf(1.f + es);
            const float nb = fmaf(sWE, ss, gv);
            const float db = fmaf(sW,  ss, den0);

#pragma unroll
            for (int uu = 0; uu < ODE_UNFOLDS; ++uu) {
                const float vp = swap_pair(v);
                const float ea = __builtin_amdgcn_exp2f(fmaf(v,  A_s, C_s));
                const float eb = __builtin_amdgcn_exp2f(fmaf(vp, A_c, C_c));
                const float a  = 1.f + ea;
                const float bb = 1.f + eb;
                const float r  = __builtin_amdgcn_rcpf(a * bb);
                const float s_s = r * bb;
                const float s_c = r * a;

                float num = fmaf(cmu, v, nb);
                num = fmaf(WE_s, s_s, num);
                num = fmaf(WE_c, s_c, num);
                float den = fmaf(W_s, s_s, db);
                den = fmaf(W_c, s_c, den);

                v = num * __builtin_amdgcn_rcpf(den);
            }
        }

#pragma unroll
        for (int k = 0; k < TU; ++k) xbuf[k] = xnext[k];
    }

    if (h == 0) {
        out[(size_t)b * d + j] = fmaf(v, output_w[j], output_b[j]);
    }
}

extern "C" void kernel_launch(void* const* d_in, const int* in_sizes, int n_in,
                              void* d_out, int out_size, void* d_ws, size_t ws_size,
                              hipStream_t stream) {
    const float* inputs   = (const float*)d_in[0];
    const float* input_w  = (const float*)d_in[1];
    const float* input_b  = (const float*)d_in[2];
    const float* output_w = (const float*)d_in[3];
    const float* output_b = (const float*)d_in[4];
    const float* gleak    = (const float*)d_in[5];
    const float* vleak    = (const float*)d_in[6];
    const float* cm       = (const float*)d_in[7];
    const float* w        = (const float*)d_in[8];
    const float* mu       = (const float*)d_in[9];
    const float* sigma    = (const float*)d_in[10];
    const float* erev     = (const float*)d_in[11];
    const float* sw       = (const float*)d_in[12];
    const float* smu      = (const float*)d_in[13];
    const float* ssig     = (const float*)d_in[14];
    const float* serev    = (const float*)d_in[15];
    float* out = (float*)d_out;

    const int d = in_sizes[1];            // input_w has shape (d,)
    const int B = out_size / d;           // out is (B, d)
    const int T = in_sizes[0] / (B * d);  // inputs is (B, T, d)

    const int total = B * 2 * d;          // one thread per (b, unit)
    const int block = 64;
    const int grid = (total + block - 1) / block;
    ltc_lane_kernel<<<grid, block, 0, stream>>>(
        inputs, input_w, input_b, output_w, output_b,
        gleak, vleak, cm, w, mu, sigma, erev,
        sw, smu, ssig, serev, out, B, T, d);
}

// Round 3
// 43.566 us; speedup vs baseline: 1.5928x; 1.0025x over previous
//
#include <hip/hip_runtime.h>

#define ODE_UNFOLDS 6
#define LTC_EPS 1e-8f

// One lane per (batch b, unit u): lane h=0 owns unit j, lane h=1 owns p=j+d
// (adjacent lanes -> partner exchange is a quad_perm DPP mov, no LDS).
//
// Chain-shortened unfold: multiply num/den through by P=(1+e_s)(1+e_x) so the
// sigmoid-normalizing rcp disappears; expand in the raw exps:
//   den' = (db+Ws+Wc) + (db+Wc)e_s + (db+Ws)e_x + db*e_s*e_x
//   num' = (t+WEs+WEc) + (t+WEc)e_s + (t+WEs)e_x + t*e_s*e_x,  t=cmu*v+nb
// Each lane computes the exp of its OUTGOING cross synapse from its own v and
// swaps the exp RESULT (not v), and next exp-args come from (A*num)*r + C so
// the v=num*r mul is off the recurrence cycle. One rcp + two exp per unfold.

__device__ __forceinline__ float swap_pair(float x) {
    // quad_perm [1,0,3,2] : lane XOR 1, full-rate v_mov_b32 dpp
    return __int_as_float(
        __builtin_amdgcn_mov_dpp(__float_as_int(x), 0xB1, 0xF, 0xF, true));
}

__global__ __launch_bounds__(64)
void ltc_lane_kernel(const float* __restrict__ inputs,
                     const float* __restrict__ input_w, const float* __restrict__ input_b,
                     const float* __restrict__ output_w, const float* __restrict__ output_b,
                     const float* __restrict__ gleak, const float* __restrict__ vleak,
                     const float* __restrict__ cm,
                     const float* __restrict__ w, const float* __restrict__ mu,
                     const float* __restrict__ sigma, const float* __restrict__ erev,
                     const float* __restrict__ sw, const float* __restrict__ smu,
                     const float* __restrict__ ssig, const float* __restrict__ serev,
                     float* __restrict__ out,
                     int B, int T, int d)
{
    const int tid = blockIdx.x * blockDim.x + threadIdx.x;
    const int units = 2 * d;
    if (tid >= B * units) return;

    const int pairIdx = tid >> 1;
    const int h = tid & 1;                 // 0 -> unit j, 1 -> unit j+d
    const int b = pairIdx / d;
    const int j = pairIdx - b * d;
    const int u  = j + h * d;              // my unit
    const int pu = j + (1 - h) * d;        // partner unit

    const float LOG2E = 1.4426950408889634f;

    // self synapse u->u: exp consts + weights
    float A_s, C_s, W_s, WE_s;
    {
        int i = u * units + u;
        float sg = sigma[i], m = mu[i];
        A_s = -sg * LOG2E; C_s = m * sg * LOG2E;
        W_s = w[i]; WE_s = W_s * erev[i];
    }
    // incoming cross synapse pu->u: weights only (exp computed by partner)
    float W_c, WE_c;
    {
        int i = pu * units + u;
        W_c = w[i]; WE_c = W_c * erev[i];
    }
    // outgoing cross synapse u->pu: exp consts only (we evaluate from own v)
    float A_o, C_o;
    {
        int i = u * units + pu;
        float sg = sigma[i], m = mu[i];
        A_o = -sg * LOG2E; C_o = m * sg * LOG2E;
    }
    const float Wsum  = W_s + W_c;
    const float WEsum = WE_s + WE_c;

    // sensory synapse j -> u, input affine folded in
    float siA, siC, sW, sWE;
    {
        int i = j * units + u;
        float sg = ssig[i], m = smu[i];
        float sA = -sg * LOG2E, sC = m * sg * LOG2E;
        const float iw = input_w[j], ib = input_b[j];
        siA = iw * sA; siC = ib * sA + sC;
        sW = sw[i]; sWE = sW * serev[i];
    }

    const float cmu = cm[u] * (float)ODE_UNFOLDS;
    const float gl  = gleak[u];
    const float gv  = gl * vleak[u];
    const float den0 = cmu + gl + LTC_EPS;   // EPS folded into den base

    const float* __restrict__ xin = inputs + (size_t)b * T * d + j;

    // recurrence state: v = num * r, with r = rcp(den)
    float num = 0.f, r = 1.f;

    const int TU = 4;                      // software-pipeline depth for x loads
    float xbuf[TU];
#pragma unroll
    for (int k = 0; k < TU; ++k) xbuf[k] = xin[(size_t)k * d];

    for (int g = 0; g < T; g += TU) {
        float xnext[TU];
        if (g + TU < T) {
#pragma unroll
            for (int k = 0; k < TU; ++k) xnext[k] = xin[(size_t)(g + TU + k) * d];
        } else {
#pragma unroll
            for (int k = 0; k < TU; ++k) xnext[k] = 0.f;
        }

#pragma unroll
        for (int k = 0; k < TU; ++k) {
            // sensory sigmoid + per-timestep bases (x-dependent only: off-chain)
            const float es_ = __builtin_amdgcn_exp2f(fmaf(xbuf[k], siA, siC));
            const float ss  = __builtin_amdgcn_rcpf(1.f + es_);
            const float nb  = fmaf(sWE, ss, gv);
            const float db  = fmaf(sW,  ss, den0);
            const float K0  = db + Wsum;
            const float Ks  = db + W_c;   // coefficient of e_s
            const float Kx  = db + W_s;   // coefficient of e_x

#pragma unroll
            for (int uu = 0; uu < ODE_UNFOLDS; ++uu) {
                const float v    = num * r;              // off critical cycle
                const float t    = fmaf(cmu, v, nb);
                const float ts   = A_s * num;            // parallel with rcp
                const float to   = A_o * num;
                const float args = fmaf(ts, r, C_s);     // = A_s*v + C_s
                const float argo = fmaf(to, r, C_o);
                const float es = __builtin_amdgcn_exp2f(args);
                const float eo = __builtin_amdgcn_exp2f(argo);
                const float ex = swap_pair(eo);          // partner's exp into me

                const float m  = es * ex;
                float dsum = fmaf(Ks, es, K0);
                dsum = fmaf(Kx, ex, dsum);
                dsum = fmaf(db, m, dsum);

                const float c1 = t + WE_c;
                const float c2 = t + WE_s;
                float nsum = fmaf(c1, es, t + WEsum);
                nsum = fmaf(c2, ex, nsum);
                nsum = fmaf(t, m, nsum);

                num = nsum;
                r = __builtin_amdgcn_rcpf(dsum);
            }
        }

#pragma unroll
        for (int k = 0; k < TU; ++k) xbuf[k] = xnext[k];
    }

    if (h == 0) {
        const float v = num * r;
        out[(size_t)b * d + j] = fmaf(v, output_w[j], output_b[j]);
    }
}

extern "C" void kernel_launch(void* const* d_in, const int* in_sizes, int n_in,
                              void* d_out, int out_size, void* d_ws, size_t ws_size,
                              hipStream_t stream) {
    const float* inputs   = (const float*)d_in[0];
    const float* input_w  = (const float*)d_in[1];
    const float* input_b  = (const float*)d_in[2];
    const float* output_w = (const float*)d_in[3];
    const float* output_b = (const float*)d_in[4];
    const float* gleak    = (const float*)d_in[5];
    const float* vleak    = (const float*)d_in[6];
    const float* cm       = (const float*)d_in[7];
    const float* w        = (const float*)d_in[8];
    const float* mu       = (const float*)d_in[9];
    const float* sigma    = (const float*)d_in[10];
    const float* erev     = (const float*)d_in[11];
    const float* sw       = (const float*)d_in[12];
    const float* smu      = (const float*)d_in[13];
    const float* ssig     = (const float*)d_in[14];
    const float* serev    = (const float*)d_in[15];
    float* out = (float*)d_out;

    const int d = in_sizes[1];            // input_w has shape (d,)
    const int B = out_size / d;           // out is (B, d)
    const int T = in_sizes[0] / (B * d);  // inputs is (B, T, d)

    const int total = B * 2 * d;          // one thread per (b, unit)
    const int block = 64;
    const int grid = (total + block - 1) / block;
    ltc_lane_kernel<<<grid, block, 0, stream>>>(
        inputs, input_w, input_b, output_w, output_b,
        gleak, vleak, cm, w, mu, sigma, erev,
        sw, smu, ssig, serev, out, B, T, d);
}